// Round 12
// baseline (214.502 us; speedup 1.0000x reference)
//
#include <hip/hip_runtime.h>
#include <hip/hip_cooperative_groups.h>
#include <hip/hip_bf16.h>

namespace cg = cooperative_groups;

#define D_FEAT 128
#define BIN_SHIFT 7
#define NODES_PER_BIN 128      // bin = node >> 7
#define BCAP 4096              // entries per bin region; avg ~1536 at E=600k,N=50k
#define EPB 2048               // edges per binning virtual block (measured-best)
#define T1 512
#define HCAP 64                // nodes per sort_gather virtual block (half a bin)
#define CSR_L_CAP 4608         // 4096 + 64*8 pad slots for a half-bin
#define OVF_CAP 4096           // overflow side-list (expected use: 0)

typedef float f2v __attribute__((ext_vector_type(2)));

// round-to-nearest-even fp32 -> bf16 bits
__device__ __forceinline__ unsigned bf16_rne(float f) {
    unsigned u = __float_as_uint(f);
    return (u + 0x7fffu + ((u >> 16) & 1u)) >> 16;
}

// ==================== FUSED cooperative kernel ====================
// phase 0: zero bin cursors (replaces hipMemsetAsync dispatch)
// phase 1: grid-stride over conv virtual blocks (h fp32 -> hb bf16) and
//          bin virtual blocks (LDS histogram -> global cursor chunk
//          reservation -> direct scatter into binned)    [= conv_bin_kernel]
// phase 2: grid-stride over NB*2 half-bin virtual blocks: LDS counting
//          sort into padded CSR + 8-wave gather of hb rows  [= sort_gather]
// grid.sync() between phases replaces the dispatch boundaries.
__global__ void __launch_bounds__(T1)
fused_kernel(const float* __restrict__ h,
             const int* __restrict__ src, const int* __restrict__ dst,
             const float* __restrict__ dt, const float* __restrict__ norm,
             const float* __restrict__ decay_lam,
             unsigned* __restrict__ hb,
             int* __restrict__ bin_cursor, unsigned long long* __restrict__ binned,
             int* __restrict__ ovf_cnt, int* __restrict__ ovf_d,
             int* __restrict__ ovf_s, float* __restrict__ ovf_w,
             float* __restrict__ out,
             int E, int HN4, int convBlocks, int binBlocks, int NB, int N) {
    cg::grid_group grid = cg::this_grid();

    __shared__ unsigned hist1[T1];
    __shared__ unsigned cur1[T1];
    __shared__ unsigned gbase1[T1];
    __shared__ unsigned hist2[HCAP];
    __shared__ unsigned padoff2[HCAP];
    __shared__ unsigned cur2[HCAP];
    __shared__ unsigned csr_l[CSR_L_CAP];

    int t = threadIdx.x;

    // ---- phase 0: zero cursors ----
    for (int i = blockIdx.x * T1 + t; i < NB; i += gridDim.x * T1)
        bin_cursor[i] = 0;
    if (blockIdx.x == 0 && t == 0) *ovf_cnt = 0;
    grid.sync();

    // ---- phase 1: conv + bin ----
    float lam = fmaxf(decay_lam[0], 0.0f) + 1e-4f;
    int p1end = convBlocks + binBlocks;
    for (int vb = blockIdx.x; vb < p1end; vb += gridDim.x) {
        if (vb < convBlocks) {
            int i = vb * T1 + t;
            if (i < HN4) {
                float4 v = ((const float4*)h)[i];
                ((uint2*)hb)[i] = make_uint2(bf16_rne(v.x) | (bf16_rne(v.y) << 16),
                                             bf16_rne(v.z) | (bf16_rne(v.w) << 16));
            }
        } else {
            int e0 = (vb - convBlocks) * EPB;
            hist1[t] = 0; cur1[t] = 0;
            __syncthreads();

            unsigned long long ent[EPB / T1];
            int bn[EPB / T1];
            #pragma unroll
            for (int k = 0; k < EPB / T1; ++k) {
                int e = e0 + k * T1 + t;
                bn[k] = -1;
                if (e < E) {
                    int s = src[e], d = dst[e];
                    float w = norm[e] * expf(-lam * dt[e]);
                    int b = d >> BIN_SHIFT;
                    int l = d & (NODES_PER_BIN - 1);
                    ent[k] = ((unsigned long long)l << 32) |
                             (((unsigned)s << 16) | bf16_rne(w));
                    bn[k] = b;
                    atomicAdd(&hist1[b], 1u);
                }
            }
            __syncthreads();

            if (t < NB && hist1[t] > 0)
                gbase1[t] = (unsigned)atomicAdd(&bin_cursor[t], (int)hist1[t]);
            __syncthreads();

            #pragma unroll
            for (int k = 0; k < EPB / T1; ++k) {
                if (bn[k] >= 0) {
                    int b = bn[k];
                    unsigned gp = gbase1[b] + atomicAdd(&cur1[b], 1u);
                    if (gp < BCAP) {
                        binned[(size_t)b * BCAP + gp] = ent[k];
                    } else {                       // bin region full (expected: never)
                        int o = atomicAdd(ovf_cnt, 1);
                        if (o < OVF_CAP) {
                            int l = (int)(ent[k] >> 32);
                            ovf_d[o] = (b << BIN_SHIFT) | l;
                            ovf_s[o] = (int)((ent[k] >> 16) & 0xFFFFu);
                            ovf_w[o] = __uint_as_float(((unsigned)ent[k] & 0xFFFFu) << 16);
                        }
                    }
                }
            }
            __syncthreads();   // before next virtual block reuses hist1/cur1
        }
    }
    grid.sync();

    // ---- phase 2: per-half-bin counting sort + gather ----
    int p2end = NB * 2;
    for (int vb = blockIdx.x; vb < p2end; vb += gridDim.x) {
        int b    = vb >> 1;
        int half = vb & 1;
        int cnt = min(bin_cursor[b], BCAP);

        if (t < HCAP) { hist2[t] = 0; cur2[t] = 0; }
        for (int i = t; i < CSR_L_CAP; i += T1) csr_l[i] = 0;  // pad = no-op edges
        __syncthreads();

        unsigned long long ent[BCAP / T1];
        size_t base_in = (size_t)b * BCAP;
        #pragma unroll
        for (int k = 0; k < BCAP / T1; ++k) {
            int idx = k * T1 + t;
            ent[k] = ~0ull;
            if (idx < cnt) {
                unsigned long long e = binned[base_in + idx];
                int l = (int)(e >> 32);
                if ((l >> 6) == half) {
                    ent[k] = e;
                    atomicAdd(&hist2[l & (HCAP - 1)], 1u);
                }
            }
        }
        __syncthreads();

        // exclusive scan of padded counts ((hist+7)&~7): 64 counts, wave-shuffle
        unsigned pc = 0, val = 0;
        if (t < HCAP) { pc = (hist2[t] + 7u) & ~7u; val = pc; }
        #pragma unroll
        for (int off = 1; off < HCAP; off <<= 1) {
            unsigned u = __shfl_up(val, off, 64);
            if ((t & 63) >= off) val += u;
        }
        if (t < HCAP) padoff2[t] = val - pc;          // exclusive
        __syncthreads();

        #pragma unroll
        for (int k = 0; k < BCAP / T1; ++k) {
            if (ent[k] != ~0ull) {
                int l = (int)(ent[k] >> 32) & (HCAP - 1);
                unsigned p = padoff2[l] + atomicAdd(&cur2[l], 1u);
                csr_l[p] = (unsigned)ent[k];
            }
        }
        __syncthreads();

        int wid = t >> 6;
        int lane = t & 63;
        int base_node = (b << BIN_SHIFT) + half * HCAP;
        int nodes = min(HCAP, N - base_node);
        bool ovf_bin = bin_cursor[b] > BCAP;

        for (int l = wid; l < nodes; l += 8) {
            unsigned base = padoff2[l];
            unsigned mr = (hist2[l] + 7u) & ~7u;
            float accx = 0.0f, accy = 0.0f;
            for (unsigned j = 0; j < mr; j += 8) {
                unsigned u0 = csr_l[base + j + 0];
                unsigned u1 = csr_l[base + j + 1];
                unsigned u2 = csr_l[base + j + 2];
                unsigned u3 = csr_l[base + j + 3];
                unsigned u4 = csr_l[base + j + 4];
                unsigned u5 = csr_l[base + j + 5];
                unsigned u6 = csr_l[base + j + 6];
                unsigned u7 = csr_l[base + j + 7];
                unsigned v0 = hb[(size_t)(u0 >> 16) * 64 + lane];
                unsigned v1 = hb[(size_t)(u1 >> 16) * 64 + lane];
                unsigned v2 = hb[(size_t)(u2 >> 16) * 64 + lane];
                unsigned v3 = hb[(size_t)(u3 >> 16) * 64 + lane];
                unsigned v4 = hb[(size_t)(u4 >> 16) * 64 + lane];
                unsigned v5 = hb[(size_t)(u5 >> 16) * 64 + lane];
                unsigned v6 = hb[(size_t)(u6 >> 16) * 64 + lane];
                unsigned v7 = hb[(size_t)(u7 >> 16) * 64 + lane];
                #define ACC(u, v)                                             \
                {   float wf = __uint_as_float((u) << 16);                    \
                    float vx = __uint_as_float((v) << 16);                    \
                    float vy = __uint_as_float((v) & 0xffff0000u);            \
                    accx += vx * wf; accy += vy * wf; }
                ACC(u0, v0) ACC(u1, v1) ACC(u2, v2) ACC(u3, v3)
                ACC(u4, v4) ACC(u5, v5) ACC(u6, v6) ACC(u7, v7)
                #undef ACC
            }
            int node = base_node + l;
            if (ovf_bin) {                             // expected: never
                int oc = min(*ovf_cnt, OVF_CAP);
                for (int o = 0; o < oc; ++o) {
                    if (ovf_d[o] == node) {
                        float we = ovf_w[o];
                        unsigned v = hb[(size_t)ovf_s[o] * 64 + lane];
                        accx += __uint_as_float(v << 16) * we;
                        accy += __uint_as_float(v & 0xffff0000u) * we;
                    }
                }
            }
            f2v r;
            r.x = accx; r.y = accy;
            __builtin_nontemporal_store(r, (f2v*)(out + (size_t)node * D_FEAT) + lane);
        }
        __syncthreads();   // before next virtual block reuses csr_l/hist2
    }
}

// ============ proven 3-dispatch fast path (fallback if coop unavailable) ============

__global__ void __launch_bounds__(T1)
conv_bin_kernel(const float* __restrict__ h,
                const int* __restrict__ src, const int* __restrict__ dst,
                const float* __restrict__ dt, const float* __restrict__ norm,
                const float* __restrict__ decay_lam,
                unsigned* __restrict__ hb,
                int* __restrict__ bin_cursor, unsigned long long* __restrict__ binned,
                int* __restrict__ ovf_cnt, int* __restrict__ ovf_d,
                int* __restrict__ ovf_s, float* __restrict__ ovf_w,
                int E, int HN4, int convBlocks, int NB) {
    __shared__ unsigned hist[T1];
    __shared__ unsigned cur[T1];
    __shared__ unsigned gbase[T1];

    int t = threadIdx.x;
    if (blockIdx.x < convBlocks) {
        int i = blockIdx.x * T1 + t;
        if (i < HN4) {
            float4 v = ((const float4*)h)[i];
            ((uint2*)hb)[i] = make_uint2(bf16_rne(v.x) | (bf16_rne(v.y) << 16),
                                         bf16_rne(v.z) | (bf16_rne(v.w) << 16));
        }
        return;
    }

    int e0 = (blockIdx.x - convBlocks) * EPB;

    hist[t] = 0; cur[t] = 0;
    __syncthreads();

    float lam = fmaxf(decay_lam[0], 0.0f) + 1e-4f;

    unsigned long long ent[EPB / T1];
    int bn[EPB / T1];
    #pragma unroll
    for (int k = 0; k < EPB / T1; ++k) {
        int e = e0 + k * T1 + t;
        bn[k] = -1;
        if (e < E) {
            int s = src[e], d = dst[e];
            float w = norm[e] * expf(-lam * dt[e]);
            int b = d >> BIN_SHIFT;
            int l = d & (NODES_PER_BIN - 1);
            ent[k] = ((unsigned long long)l << 32) | (((unsigned)s << 16) | bf16_rne(w));
            bn[k] = b;
            atomicAdd(&hist[b], 1u);
        }
    }
    __syncthreads();

    if (t < NB && hist[t] > 0)
        gbase[t] = (unsigned)atomicAdd(&bin_cursor[t], (int)hist[t]);
    __syncthreads();

    #pragma unroll
    for (int k = 0; k < EPB / T1; ++k) {
        if (bn[k] >= 0) {
            int b = bn[k];
            unsigned gp = gbase[b] + atomicAdd(&cur[b], 1u);
            if (gp < BCAP) {
                binned[(size_t)b * BCAP + gp] = ent[k];
            } else {
                int o = atomicAdd(ovf_cnt, 1);
                if (o < OVF_CAP) {
                    int l = (int)(ent[k] >> 32);
                    ovf_d[o] = (b << BIN_SHIFT) | l;
                    ovf_s[o] = (int)((ent[k] >> 16) & 0xFFFFu);
                    ovf_w[o] = __uint_as_float(((unsigned)ent[k] & 0xFFFFu) << 16);
                }
            }
        }
    }
}

__global__ void __launch_bounds__(T1)
sort_gather_kernel(const unsigned long long* __restrict__ binned,
                   const int* __restrict__ bin_cursor,
                   const unsigned* __restrict__ hb,
                   const int* __restrict__ ovf_cnt, const int* __restrict__ ovf_d,
                   const int* __restrict__ ovf_s, const float* __restrict__ ovf_w,
                   float* __restrict__ out, int N) {
    __shared__ unsigned hist[HCAP];
    __shared__ unsigned padoff[HCAP];
    __shared__ unsigned cur[HCAP];
    __shared__ unsigned csr_l[CSR_L_CAP];

    int b    = blockIdx.x >> 1;
    int half = blockIdx.x & 1;
    int t = threadIdx.x;
    int cnt = min(bin_cursor[b], BCAP);

    if (t < HCAP) { hist[t] = 0; cur[t] = 0; }
    for (int i = t; i < CSR_L_CAP; i += T1) csr_l[i] = 0;
    __syncthreads();

    unsigned long long ent[BCAP / T1];
    size_t base_in = (size_t)b * BCAP;
    #pragma unroll
    for (int k = 0; k < BCAP / T1; ++k) {
        int idx = k * T1 + t;
        ent[k] = ~0ull;
        if (idx < cnt) {
            unsigned long long e = binned[base_in + idx];
            int l = (int)(e >> 32);
            if ((l >> 6) == half) {
                ent[k] = e;
                atomicAdd(&hist[l & (HCAP - 1)], 1u);
            }
        }
    }
    __syncthreads();

    unsigned pc = 0, val = 0;
    if (t < HCAP) { pc = (hist[t] + 7u) & ~7u; val = pc; }
    #pragma unroll
    for (int off = 1; off < HCAP; off <<= 1) {
        unsigned u = __shfl_up(val, off, 64);
        if ((t & 63) >= off) val += u;
    }
    if (t < HCAP) padoff[t] = val - pc;
    __syncthreads();

    #pragma unroll
    for (int k = 0; k < BCAP / T1; ++k) {
        if (ent[k] != ~0ull) {
            int l = (int)(ent[k] >> 32) & (HCAP - 1);
            unsigned p = padoff[l] + atomicAdd(&cur[l], 1u);
            csr_l[p] = (unsigned)ent[k];
        }
    }
    __syncthreads();

    int wid = t >> 6;
    int lane = t & 63;
    int base_node = (b << BIN_SHIFT) + half * HCAP;
    int nodes = min(HCAP, N - base_node);
    bool ovf_bin = bin_cursor[b] > BCAP;

    for (int l = wid; l < nodes; l += 8) {
        unsigned base = padoff[l];
        unsigned mr = (hist[l] + 7u) & ~7u;
        float accx = 0.0f, accy = 0.0f;
        for (unsigned j = 0; j < mr; j += 8) {
            unsigned u0 = csr_l[base + j + 0];
            unsigned u1 = csr_l[base + j + 1];
            unsigned u2 = csr_l[base + j + 2];
            unsigned u3 = csr_l[base + j + 3];
            unsigned u4 = csr_l[base + j + 4];
            unsigned u5 = csr_l[base + j + 5];
            unsigned u6 = csr_l[base + j + 6];
            unsigned u7 = csr_l[base + j + 7];
            unsigned v0 = hb[(size_t)(u0 >> 16) * 64 + lane];
            unsigned v1 = hb[(size_t)(u1 >> 16) * 64 + lane];
            unsigned v2 = hb[(size_t)(u2 >> 16) * 64 + lane];
            unsigned v3 = hb[(size_t)(u3 >> 16) * 64 + lane];
            unsigned v4 = hb[(size_t)(u4 >> 16) * 64 + lane];
            unsigned v5 = hb[(size_t)(u5 >> 16) * 64 + lane];
            unsigned v6 = hb[(size_t)(u6 >> 16) * 64 + lane];
            unsigned v7 = hb[(size_t)(u7 >> 16) * 64 + lane];
            #define ACC(u, v)                                             \
            {   float wf = __uint_as_float((u) << 16);                    \
                float vx = __uint_as_float((v) << 16);                    \
                float vy = __uint_as_float((v) & 0xffff0000u);            \
                accx += vx * wf; accy += vy * wf; }
            ACC(u0, v0) ACC(u1, v1) ACC(u2, v2) ACC(u3, v3)
            ACC(u4, v4) ACC(u5, v5) ACC(u6, v6) ACC(u7, v7)
            #undef ACC
        }
        int node = base_node + l;
        if (ovf_bin) {
            int oc = min(*ovf_cnt, OVF_CAP);
            for (int o = 0; o < oc; ++o) {
                if (ovf_d[o] == node) {
                    float we = ovf_w[o];
                    unsigned v = hb[(size_t)ovf_s[o] * 64 + lane];
                    accx += __uint_as_float(v << 16) * we;
                    accy += __uint_as_float(v & 0xffff0000u) * we;
                }
            }
        }
        f2v r;
        r.x = accx; r.y = accy;
        __builtin_nontemporal_store(r, (f2v*)(out + (size_t)node * D_FEAT) + lane);
    }
}

// ================== FALLBACK PATH: compact CSR (fp32, exact) ==================

__global__ void degree_kernel(const int* __restrict__ dst, int* __restrict__ deg, int E) {
    int e = blockIdx.x * blockDim.x + threadIdx.x;
    if (e >= E) return;
    atomicAdd(&deg[dst[e]], 1);
}

__global__ void scan_blocks(const int* __restrict__ deg, int* __restrict__ offs,
                            int* __restrict__ blockSums, int N) {
    __shared__ int tmp[256];
    int tid = threadIdx.x;
    int gid = blockIdx.x * 256 + tid;
    int v = (gid < N) ? deg[gid] : 0;
    tmp[tid] = v;
    __syncthreads();
    for (int off = 1; off < 256; off <<= 1) {
        int t = (tid >= off) ? tmp[tid - off] : 0;
        __syncthreads();
        tmp[tid] += t;
        __syncthreads();
    }
    if (gid < N) offs[gid] = tmp[tid] - v;
    if (tid == 255) blockSums[blockIdx.x] = tmp[255];
}

__global__ void scan_sums(int* __restrict__ blockSums, int* __restrict__ blockOffs, int nb) {
    __shared__ int tmp[256];
    int tid = threadIdx.x;
    int v = (tid < nb) ? blockSums[tid] : 0;
    tmp[tid] = v;
    __syncthreads();
    for (int off = 1; off < 256; off <<= 1) {
        int t = (tid >= off) ? tmp[tid - off] : 0;
        __syncthreads();
        tmp[tid] += t;
        __syncthreads();
    }
    if (tid < nb) blockOffs[tid] = tmp[tid] - v;
}

__global__ void scan_fixup(int* __restrict__ offs, const int* __restrict__ blockOffs,
                           int* __restrict__ cursor, int N) {
    int gid = blockIdx.x * 256 + threadIdx.x;
    if (gid >= N) return;
    int o = offs[gid] + blockOffs[blockIdx.x];
    offs[gid] = o;
    cursor[gid] = o;
}

__global__ void bucket_kernel(const int* __restrict__ src, const int* __restrict__ dst,
                              const float* __restrict__ dt, const float* __restrict__ norm,
                              const float* __restrict__ decay_lam,
                              int* __restrict__ cursor, float2* __restrict__ pairs, int E) {
    int e = blockIdx.x * blockDim.x + threadIdx.x;
    if (e >= E) return;
    float lam = fmaxf(decay_lam[0], 0.0f) + 1e-4f;
    float w = norm[e] * expf(-lam * dt[e]);
    int d = dst[e];
    int pos = atomicAdd(&cursor[d], 1);
    float2 p;
    p.x = __int_as_float(src[e]);
    p.y = w;
    pairs[pos] = p;
}

__global__ void __launch_bounds__(256)
gather_kernel(const float* __restrict__ h,
              const int* __restrict__ offs, const int* __restrict__ deg,
              const float2* __restrict__ pairs, float* __restrict__ out, int N) {
    int node = blockIdx.x * 4 + (threadIdx.x >> 6);
    if (node >= N) return;
    int lane = threadIdx.x & 63;
    int start = offs[node];
    int end = start + deg[node];
    float accx = 0.0f, accy = 0.0f;
    for (int j = start; j < end; ++j) {
        float2 p = pairs[j];
        int s = __float_as_int(p.x);
        float we = p.y;
        float2 v = ((const float2*)(h + (size_t)s * D_FEAT))[lane];
        accx += v.x * we;
        accy += v.y * we;
    }
    float2 r; r.x = accx; r.y = accy;
    ((float2*)(out + (size_t)node * D_FEAT))[lane] = r;
}

extern "C" void kernel_launch(void* const* d_in, const int* in_sizes, int n_in,
                              void* d_out, int out_size, void* d_ws, size_t ws_size,
                              hipStream_t stream) {
    const float* h         = (const float*)d_in[0];
    const int*   src       = (const int*)d_in[1];
    const int*   dst       = (const int*)d_in[2];
    const float* dt        = (const float*)d_in[3];
    const float* norm      = (const float*)d_in[4];
    const float* decay_lam = (const float*)d_in[5];
    float* out = (float*)d_out;

    const int E  = in_sizes[1];
    const int HN = in_sizes[0];
    const int N  = out_size / D_FEAT;
    const int NB = (N + NODES_PER_BIN - 1) >> BIN_SHIFT;

    auto align64 = [](size_t x) { return (x + 63) & ~(size_t)63; };
    size_t sz_binc = align64((size_t)NB * 4);
    size_t sz_ovfc = 64;
    size_t sz_ovf  = align64((size_t)OVF_CAP * 4);
    size_t sz_binn = align64((size_t)NB * BCAP * 8);
    size_t sz_hb   = align64((size_t)HN * 2);
    size_t need = sz_binc + sz_ovfc + 3 * sz_ovf + sz_binn + sz_hb;

    if (ws_size >= need && N <= 65536 && (HN & 3) == 0 && NB <= T1) {
        char* ws = (char*)d_ws;
        int* bin_cursor = (int*)ws;                 ws += sz_binc;
        int* ovf_cnt    = (int*)ws;                 ws += sz_ovfc;
        int* ovf_d      = (int*)ws;                 ws += sz_ovf;
        int* ovf_s      = (int*)ws;                 ws += sz_ovf;
        float* ovf_w    = (float*)ws;               ws += sz_ovf;
        unsigned long long* binned = (unsigned long long*)ws;  ws += sz_binn;
        unsigned* hb    = (unsigned*)ws;

        const int HN4 = HN / 4;
        int convBlocks = (HN4 + T1 - 1) / T1;
        int binBlocks  = (E + EPB - 1) / EPB;

        // one-time capability + occupancy query (host-side, cached)
        static int coopGrid = -2;                   // -2 = not probed
        if (coopGrid == -2) {
            int dev = 0;
            hipGetDevice(&dev);
            hipDeviceProp_t props{};
            if (hipGetDeviceProperties(&props, dev) == hipSuccess &&
                props.cooperativeLaunch) {
                int perCU = 0;
                if (hipOccupancyMaxActiveBlocksPerMultiprocessor(
                        &perCU, reinterpret_cast<const void*>(fused_kernel),
                        T1, 0) == hipSuccess && perCU > 0) {
                    long g = (long)perCU * props.multiProcessorCount;
                    if (g > 1024) g = 1024;
                    coopGrid = (int)g;
                } else coopGrid = -1;
            } else coopGrid = -1;
            (void)hipGetLastError();
        }

        if (coopGrid > 0) {
            int E_ = E, HN4_ = HN4, cb_ = convBlocks, bb_ = binBlocks,
                NB_ = NB, N_ = N;
            void* args[] = { &h, &src, &dst, &dt, &norm, &decay_lam,
                             &hb, &bin_cursor, &binned,
                             &ovf_cnt, &ovf_d, &ovf_s, &ovf_w, &out,
                             &E_, &HN4_, &cb_, &bb_, &NB_, &N_ };
            hipError_t le = hipLaunchCooperativeKernel(
                reinterpret_cast<const void*>(fused_kernel),
                dim3(coopGrid), dim3(T1), args, 0, stream);
            if (le == hipSuccess) return;
            (void)hipGetLastError();                // fall through to 3-dispatch path
        }

        hipMemsetAsync(bin_cursor, 0, sz_binc + sz_ovfc, stream);
        conv_bin_kernel<<<convBlocks + binBlocks, T1, 0, stream>>>(
            h, src, dst, dt, norm, decay_lam, hb, bin_cursor, binned,
            ovf_cnt, ovf_d, ovf_s, ovf_w, E, HN4, convBlocks, NB);
        sort_gather_kernel<<<NB * 2, T1, 0, stream>>>(
            binned, bin_cursor, hb, ovf_cnt, ovf_d, ovf_s, ovf_w, out, N);
    } else {
        // -------- fallback: compact CSR with hierarchical scan (fp32 exact) --------
        const int nb = (N + 255) / 256;
        char* ws = (char*)d_ws;
        int*    dega      = (int*)ws;     ws += (size_t)N * 4;
        int*    offsa     = (int*)ws;     ws += (size_t)N * 4;
        int*    cursor    = (int*)ws;     ws += (size_t)N * 4;
        int*    blockSums = (int*)ws;     ws += 256 * 4;
        int*    blockOffs = (int*)ws;     ws += 256 * 4;
        float2* pairs     = (float2*)ws;

        hipMemsetAsync(dega, 0, (size_t)N * 4, stream);
        degree_kernel<<<(E + 255) / 256, 256, 0, stream>>>(dst, dega, E);
        scan_blocks<<<nb, 256, 0, stream>>>(dega, offsa, blockSums, N);
        scan_sums<<<1, 256, 0, stream>>>(blockSums, blockOffs, nb);
        scan_fixup<<<nb, 256, 0, stream>>>(offsa, blockOffs, cursor, N);
        bucket_kernel<<<(E + 255) / 256, 256, 0, stream>>>(
            src, dst, dt, norm, decay_lam, cursor, pairs, E);
        gather_kernel<<<(N + 3) / 4, 256, 0, stream>>>(h, offsa, dega, pairs, out, N);
    }
}

// Round 13
// 140.502 us; speedup vs baseline: 1.5267x; 1.5267x over previous
//
#include <hip/hip_runtime.h>
#include <hip/hip_bf16.h>

#define D_FEAT 128
#define BIN_SHIFT 7
#define NODES_PER_BIN 128      // bin = node >> 7
#define BCAP 4096              // entries per bin region; avg ~1536 at E=600k,N=50k
#define EPB 2048               // edges per binning block (measured-best config)
#define T1 512
#define CSR_L_CAP 5120         // 4096 + 128*7 padding slots
#define OVF_CAP 4096           // overflow side-list (expected use: 0)

typedef float f2v __attribute__((ext_vector_type(2)));

// round-to-nearest-even fp32 -> bf16 bits
__device__ __forceinline__ unsigned bf16_rne(float f) {
    unsigned u = __float_as_uint(f);
    return (u + 0x7fffu + ((u >> 16) & 1u)) >> 16;
}

// ---- fast kernel 1: binning only (conv stage ELIMINATED) ----
// Bin edges by dst>>7. LDS histogram -> one global cursor atomic per
// (block,bin) reserves a contiguous chunk -> per-edge direct scatter.
// Entry: [l:7b << 32 | src:16b << 16 | w:bf16]. The gather now reads
// fp32 h directly (latency-bound, so 2x bytes is ~free), which removes
// the h->bf16 conversion stage (38.4MB traffic + a serial pipeline stage).
__global__ void __launch_bounds__(T1)
bin_kernel(const int* __restrict__ src, const int* __restrict__ dst,
           const float* __restrict__ dt, const float* __restrict__ norm,
           const float* __restrict__ decay_lam,
           int* __restrict__ bin_cursor, unsigned long long* __restrict__ binned,
           int* __restrict__ ovf_cnt, int* __restrict__ ovf_d,
           int* __restrict__ ovf_s, float* __restrict__ ovf_w,
           int E, int NB) {
    __shared__ unsigned hist[T1];
    __shared__ unsigned cur[T1];
    __shared__ unsigned gbase[T1];

    int t = threadIdx.x;
    int e0 = blockIdx.x * EPB;

    hist[t] = 0; cur[t] = 0;
    __syncthreads();

    float lam = fmaxf(decay_lam[0], 0.0f) + 1e-4f;

    unsigned long long ent[EPB / T1];
    int bn[EPB / T1];
    #pragma unroll
    for (int k = 0; k < EPB / T1; ++k) {
        int e = e0 + k * T1 + t;
        bn[k] = -1;
        if (e < E) {
            int s = src[e], d = dst[e];
            float w = norm[e] * expf(-lam * dt[e]);
            int b = d >> BIN_SHIFT;
            int l = d & (NODES_PER_BIN - 1);
            ent[k] = ((unsigned long long)l << 32) | (((unsigned)s << 16) | bf16_rne(w));
            bn[k] = b;
            atomicAdd(&hist[b], 1u);
        }
    }
    __syncthreads();

    if (t < NB && hist[t] > 0)
        gbase[t] = (unsigned)atomicAdd(&bin_cursor[t], (int)hist[t]);
    __syncthreads();

    #pragma unroll
    for (int k = 0; k < EPB / T1; ++k) {
        if (bn[k] >= 0) {
            int b = bn[k];
            unsigned gp = gbase[b] + atomicAdd(&cur[b], 1u);
            if (gp < BCAP) {
                binned[(size_t)b * BCAP + gp] = ent[k];
            } else {                               // bin region full (expected: never)
                int o = atomicAdd(ovf_cnt, 1);
                if (o < OVF_CAP) {
                    int l = (int)(ent[k] >> 32);
                    ovf_d[o] = (b << BIN_SHIFT) | l;
                    ovf_s[o] = (int)((ent[k] >> 16) & 0xFFFFu);
                    ovf_w[o] = __uint_as_float(((unsigned)ent[k] & 0xFFFFu) << 16);
                }
            }
        }
    }
}

// ---- fast kernel 2: per-bin LDS counting-sort + gather (from fp32 h) ----
// Identical to the measured 127.16us structure except the gather loads
// float2 from h (8B/lane) instead of packed bf16 from hb (4B/lane).
// Latency-bound gather -> wider loads are ~free; h is exact (absmax drops).
__global__ void __launch_bounds__(T1)
sort_gather_kernel(const unsigned long long* __restrict__ binned,
                   const int* __restrict__ bin_cursor,
                   const float* __restrict__ h,
                   const int* __restrict__ ovf_cnt, const int* __restrict__ ovf_d,
                   const int* __restrict__ ovf_s, const float* __restrict__ ovf_w,
                   float* __restrict__ out, int N) {
    __shared__ unsigned hist[NODES_PER_BIN];
    __shared__ unsigned padoff[NODES_PER_BIN];
    __shared__ unsigned cur[NODES_PER_BIN];
    __shared__ unsigned csr_l[CSR_L_CAP];
    __shared__ unsigned wtot;

    int b = blockIdx.x;
    int t = threadIdx.x;
    int cnt = min(bin_cursor[b], BCAP);

    if (t < NODES_PER_BIN) { hist[t] = 0; cur[t] = 0; }
    for (int i = t; i < CSR_L_CAP; i += T1) csr_l[i] = 0;  // pad slots = no-op edges
    __syncthreads();

    // load bin entries into registers + LDS histogram
    unsigned long long ent[BCAP / T1];
    size_t base_in = (size_t)b * BCAP;
    #pragma unroll
    for (int k = 0; k < BCAP / T1; ++k) {
        int idx = k * T1 + t;
        ent[k] = ~0ull;
        if (idx < cnt) {
            unsigned long long e = binned[base_in + idx];
            ent[k] = e;
            atomicAdd(&hist[(int)(e >> 32)], 1u);
        }
    }
    __syncthreads();

    // exclusive scan of padded counts ((hist+7)&~7) via wave shuffles
    unsigned pc = 0, val = 0;
    if (t < NODES_PER_BIN) { pc = (hist[t] + 7u) & ~7u; val = pc; }
    #pragma unroll
    for (int off = 1; off < 64; off <<= 1) {
        unsigned u = __shfl_up(val, off, 64);
        if ((t & 63) >= off) val += u;
    }
    if (t == 63) wtot = val;                      // wave 0 total
    __syncthreads();
    if (t < NODES_PER_BIN)
        padoff[t] = val + ((t >= 64) ? wtot : 0u) - pc;   // exclusive
    __syncthreads();

    // reorder into LDS padded CSR
    #pragma unroll
    for (int k = 0; k < BCAP / T1; ++k) {
        if (ent[k] != ~0ull) {
            int l = (int)(ent[k] >> 32);
            unsigned p = padoff[l] + atomicAdd(&cur[l], 1u);
            csr_l[p] = (unsigned)ent[k];
        }
    }
    __syncthreads();

    // gather: 8 waves, nodes strided by 8; float2 loads straight from h
    int wid = t >> 6;
    int lane = t & 63;
    int nodes = min(NODES_PER_BIN, N - (b << BIN_SHIFT));
    bool ovf_bin = bin_cursor[b] > BCAP;

    for (int l = wid; l < nodes; l += 8) {
        unsigned base = padoff[l];
        unsigned mr = (hist[l] + 7u) & ~7u;
        float accx = 0.0f, accy = 0.0f;
        for (unsigned j = 0; j < mr; j += 8) {
            unsigned u0 = csr_l[base + j + 0];
            unsigned u1 = csr_l[base + j + 1];
            unsigned u2 = csr_l[base + j + 2];
            unsigned u3 = csr_l[base + j + 3];
            unsigned u4 = csr_l[base + j + 4];
            unsigned u5 = csr_l[base + j + 5];
            unsigned u6 = csr_l[base + j + 6];
            unsigned u7 = csr_l[base + j + 7];
            float2 v0 = ((const float2*)(h + (size_t)(u0 >> 16) * D_FEAT))[lane];
            float2 v1 = ((const float2*)(h + (size_t)(u1 >> 16) * D_FEAT))[lane];
            float2 v2 = ((const float2*)(h + (size_t)(u2 >> 16) * D_FEAT))[lane];
            float2 v3 = ((const float2*)(h + (size_t)(u3 >> 16) * D_FEAT))[lane];
            float2 v4 = ((const float2*)(h + (size_t)(u4 >> 16) * D_FEAT))[lane];
            float2 v5 = ((const float2*)(h + (size_t)(u5 >> 16) * D_FEAT))[lane];
            float2 v6 = ((const float2*)(h + (size_t)(u6 >> 16) * D_FEAT))[lane];
            float2 v7 = ((const float2*)(h + (size_t)(u7 >> 16) * D_FEAT))[lane];
            #define ACC(u, v)                                             \
            {   float wf = __uint_as_float((u) << 16);                    \
                accx += (v).x * wf; accy += (v).y * wf; }
            ACC(u0, v0) ACC(u1, v1) ACC(u2, v2) ACC(u3, v3)
            ACC(u4, v4) ACC(u5, v5) ACC(u6, v6) ACC(u7, v7)
            #undef ACC
        }
        int node = (b << BIN_SHIFT) + l;
        if (ovf_bin) {                             // expected: never
            int oc = min(*ovf_cnt, OVF_CAP);
            for (int o = 0; o < oc; ++o) {
                if (ovf_d[o] == node) {
                    float we = ovf_w[o];
                    float2 v = ((const float2*)(h + (size_t)ovf_s[o] * D_FEAT))[lane];
                    accx += v.x * we;
                    accy += v.y * we;
                }
            }
        }
        f2v r;
        r.x = accx; r.y = accy;
        __builtin_nontemporal_store(r, (f2v*)(out + (size_t)node * D_FEAT) + lane);
    }
}

// ================== FALLBACK PATH: compact CSR (fp32, exact) ==================

__global__ void degree_kernel(const int* __restrict__ dst, int* __restrict__ deg, int E) {
    int e = blockIdx.x * blockDim.x + threadIdx.x;
    if (e >= E) return;
    atomicAdd(&deg[dst[e]], 1);
}

__global__ void scan_blocks(const int* __restrict__ deg, int* __restrict__ offs,
                            int* __restrict__ blockSums, int N) {
    __shared__ int tmp[256];
    int tid = threadIdx.x;
    int gid = blockIdx.x * 256 + tid;
    int v = (gid < N) ? deg[gid] : 0;
    tmp[tid] = v;
    __syncthreads();
    for (int off = 1; off < 256; off <<= 1) {
        int t = (tid >= off) ? tmp[tid - off] : 0;
        __syncthreads();
        tmp[tid] += t;
        __syncthreads();
    }
    if (gid < N) offs[gid] = tmp[tid] - v;
    if (tid == 255) blockSums[blockIdx.x] = tmp[255];
}

__global__ void scan_sums(int* __restrict__ blockSums, int* __restrict__ blockOffs, int nb) {
    __shared__ int tmp[256];
    int tid = threadIdx.x;
    int v = (tid < nb) ? blockSums[tid] : 0;
    tmp[tid] = v;
    __syncthreads();
    for (int off = 1; off < 256; off <<= 1) {
        int t = (tid >= off) ? tmp[tid - off] : 0;
        __syncthreads();
        tmp[tid] += t;
        __syncthreads();
    }
    if (tid < nb) blockOffs[tid] = tmp[tid] - v;
}

__global__ void scan_fixup(int* __restrict__ offs, const int* __restrict__ blockOffs,
                           int* __restrict__ cursor, int N) {
    int gid = blockIdx.x * 256 + threadIdx.x;
    if (gid >= N) return;
    int o = offs[gid] + blockOffs[blockIdx.x];
    offs[gid] = o;
    cursor[gid] = o;
}

__global__ void bucket_kernel(const int* __restrict__ src, const int* __restrict__ dst,
                              const float* __restrict__ dt, const float* __restrict__ norm,
                              const float* __restrict__ decay_lam,
                              int* __restrict__ cursor, float2* __restrict__ pairs, int E) {
    int e = blockIdx.x * blockDim.x + threadIdx.x;
    if (e >= E) return;
    float lam = fmaxf(decay_lam[0], 0.0f) + 1e-4f;
    float w = norm[e] * expf(-lam * dt[e]);
    int d = dst[e];
    int pos = atomicAdd(&cursor[d], 1);
    float2 p;
    p.x = __int_as_float(src[e]);
    p.y = w;
    pairs[pos] = p;
}

__global__ void __launch_bounds__(256)
gather_kernel(const float* __restrict__ h,
              const int* __restrict__ offs, const int* __restrict__ deg,
              const float2* __restrict__ pairs, float* __restrict__ out, int N) {
    int node = blockIdx.x * 4 + (threadIdx.x >> 6);
    if (node >= N) return;
    int lane = threadIdx.x & 63;
    int start = offs[node];
    int end = start + deg[node];
    float accx = 0.0f, accy = 0.0f;
    for (int j = start; j < end; ++j) {
        float2 p = pairs[j];
        int s = __float_as_int(p.x);
        float we = p.y;
        float2 v = ((const float2*)(h + (size_t)s * D_FEAT))[lane];
        accx += v.x * we;
        accy += v.y * we;
    }
    float2 r; r.x = accx; r.y = accy;
    ((float2*)(out + (size_t)node * D_FEAT))[lane] = r;
}

extern "C" void kernel_launch(void* const* d_in, const int* in_sizes, int n_in,
                              void* d_out, int out_size, void* d_ws, size_t ws_size,
                              hipStream_t stream) {
    const float* h         = (const float*)d_in[0];
    const int*   src       = (const int*)d_in[1];
    const int*   dst       = (const int*)d_in[2];
    const float* dt        = (const float*)d_in[3];
    const float* norm      = (const float*)d_in[4];
    const float* decay_lam = (const float*)d_in[5];
    float* out = (float*)d_out;

    const int E  = in_sizes[1];
    const int N  = out_size / D_FEAT;
    const int NB = (N + NODES_PER_BIN - 1) >> BIN_SHIFT;

    auto align64 = [](size_t x) { return (x + 63) & ~(size_t)63; };
    size_t sz_binc = align64((size_t)NB * 4);
    size_t sz_ovfc = 64;
    size_t sz_ovf  = align64((size_t)OVF_CAP * 4);
    size_t sz_binn = align64((size_t)NB * BCAP * 8);
    size_t need = sz_binc + sz_ovfc + 3 * sz_ovf + sz_binn;

    if (ws_size >= need && N <= 65536 && NB <= T1) {
        char* ws = (char*)d_ws;
        int* bin_cursor = (int*)ws;                 ws += sz_binc;
        int* ovf_cnt    = (int*)ws;                 ws += sz_ovfc;
        int* ovf_d      = (int*)ws;                 ws += sz_ovf;
        int* ovf_s      = (int*)ws;                 ws += sz_ovf;
        float* ovf_w    = (float*)ws;               ws += sz_ovf;
        unsigned long long* binned = (unsigned long long*)ws;

        hipMemsetAsync(bin_cursor, 0, sz_binc + sz_ovfc, stream);

        const int binBlocks = (E + EPB - 1) / EPB;
        bin_kernel<<<binBlocks, T1, 0, stream>>>(
            src, dst, dt, norm, decay_lam, bin_cursor, binned,
            ovf_cnt, ovf_d, ovf_s, ovf_w, E, NB);

        sort_gather_kernel<<<NB, T1, 0, stream>>>(
            binned, bin_cursor, h, ovf_cnt, ovf_d, ovf_s, ovf_w, out, N);
    } else {
        // -------- fallback: compact CSR with hierarchical scan (fp32 exact) --------
        const int nb = (N + 255) / 256;
        char* ws = (char*)d_ws;
        int*    dega      = (int*)ws;     ws += (size_t)N * 4;
        int*    offsa     = (int*)ws;     ws += (size_t)N * 4;
        int*    cursor    = (int*)ws;     ws += (size_t)N * 4;
        int*    blockSums = (int*)ws;     ws += 256 * 4;
        int*    blockOffs = (int*)ws;     ws += 256 * 4;
        float2* pairs     = (float2*)ws;

        hipMemsetAsync(dega, 0, (size_t)N * 4, stream);
        degree_kernel<<<(E + 255) / 256, 256, 0, stream>>>(dst, dega, E);
        scan_blocks<<<nb, 256, 0, stream>>>(dega, offsa, blockSums, N);
        scan_sums<<<1, 256, 0, stream>>>(blockSums, blockOffs, nb);
        scan_fixup<<<nb, 256, 0, stream>>>(offsa, blockOffs, cursor, N);
        bucket_kernel<<<(E + 255) / 256, 256, 0, stream>>>(
            src, dst, dt, norm, decay_lam, cursor, pairs, E);
        gather_kernel<<<(N + 3) / 4, 256, 0, stream>>>(h, offsa, dega, pairs, out, N);
    }
}